// Round 3
// baseline (11924.710 us; speedup 1.0000x reference)
//
#include <hip/hip_runtime.h>
#include <math.h>

// 2-layer LSTM (B=1024,T=512,F=64,H=128) + FC head, fp32.
// R3: (1) input projections of BOTH layers hoisted to parallel GEMMs (rec K=128);
// (2) recurrence: 256 thr/block, 2 cols/thread, weights in 256 VGPRs at
// launch_bounds(256,1) (cap 512, no allocator pressure), DS broadcasts per CU
// per step cut 3x (1536->512), each ds_read_b128 feeds 8 FMAs;
// (3) v_pk_fma_f32 via float2 __builtin_elementwise_fma.

#define BB 1024
#define TT 512
#define FF 64
#define HH 128
#define GG 512  // 4*H

typedef float v2f __attribute__((ext_vector_type(2)));

__device__ __forceinline__ v2f pkfma(v2f a, v2f b, v2f c) {
#if __has_builtin(__builtin_elementwise_fma)
    return __builtin_elementwise_fma(a, b, c);
#else
    v2f r; r.x = fmaf(a.x, b.x, c.x); r.y = fmaf(a.y, b.y, c.y); return r;
#endif
}

__device__ __forceinline__ float sigmoidf_(float x) {
    return 1.0f / (1.0f + __expf(-x));
}
__device__ __forceinline__ float tanhf_(float x) {
    return 1.0f - 2.0f / (1.0f + __expf(2.0f * x));
}

// ---------------- recurrence (shared by both layers), K=128 -----------------
// 256 threads; thread t owns gate columns t and t+256; block owns 4 batch rows.
__global__ __launch_bounds__(256, 1) void rec_kernel(
    const float* __restrict__ xp,   // [B*TC][512] pre-activations (biases included)
    const float* __restrict__ Whh,  // [512][128]
    float* __restrict__ hs, float* __restrict__ cs,   // [B][128] states
    float* __restrict__ h1c,        // [B*TC][128] or null
    int TC, int store_h)
{
    const int t = threadIdx.x;
    const int blk = blockIdx.x;
    const long b0 = (long)blk * 4;
    const int j0 = t, j1 = t + 256;

    float wA[HH], wB[HH];
#pragma unroll
    for (int q = 0; q < HH / 4; ++q)
        *(float4*)&wA[4 * q] = *(const float4*)&Whh[(long)j0 * HH + 4 * q];
#pragma unroll
    for (int q = 0; q < HH / 4; ++q)
        *(float4*)&wB[4 * q] = *(const float4*)&Whh[(long)j1 * HH + 4 * q];

    __shared__ __align__(16) float h_lds[HH * 4];   // [k][m]
    __shared__ __align__(16) float pre[GG * 4];     // [j][m]

    // init h_lds: h_lds[k*4+m] = hs[(b0+m)*HH+k]; linear e = k*4+m
#pragma unroll
    for (int i = 0; i < 2; ++i) {
        int e = t + 256 * i;
        int m = e & 3, k = e >> 2;
        h_lds[e] = hs[(b0 + m) * HH + k];
    }
    const int gm = t >> 7;       // 0..1
    const int ghj = t & 127;     // h index
    float c0 = cs[(b0 + gm) * HH + ghj];
    float c1 = cs[(b0 + gm + 2) * HH + ghj];
    __syncthreads();

    for (int tt = 0; tt < TC; ++tt) {
        const long r0 = b0 * TC + tt;  // row of batch b0
        // init accumulators with xp (bias already folded in)
        v2f a00, a01, a10, a11;
        a00.x = xp[(r0 + 0 * TC) * GG + j0]; a00.y = xp[(r0 + 1 * TC) * GG + j0];
        a01.x = xp[(r0 + 2 * TC) * GG + j0]; a01.y = xp[(r0 + 3 * TC) * GG + j0];
        a10.x = xp[(r0 + 0 * TC) * GG + j1]; a10.y = xp[(r0 + 1 * TC) * GG + j1];
        a11.x = xp[(r0 + 2 * TC) * GG + j1]; a11.y = xp[(r0 + 3 * TC) * GG + j1];

#pragma unroll
        for (int k = 0; k < HH; ++k) {
            float4 h4 = *(const float4*)&h_lds[k * 4];
            v2f h01; h01.x = h4.x; h01.y = h4.y;
            v2f h23; h23.x = h4.z; h23.y = h4.w;
            v2f wa; wa.x = wA[k]; wa.y = wA[k];
            v2f wb; wb.x = wB[k]; wb.y = wB[k];
            a00 = pkfma(wa, h01, a00);
            a01 = pkfma(wa, h23, a01);
            a10 = pkfma(wb, h01, a10);
            a11 = pkfma(wb, h23, a11);
        }
        *(float4*)&pre[j0 * 4] = make_float4(a00.x, a00.y, a01.x, a01.y);
        *(float4*)&pre[j1 * 4] = make_float4(a10.x, a10.y, a11.x, a11.y);
        __syncthreads();

        // gate phase: thread handles (gm, ghj) and (gm+2, ghj)
        {
            float pi = pre[(ghj)*4 + gm];
            float pf = pre[(ghj + 128) * 4 + gm];
            float pg = pre[(ghj + 256) * 4 + gm];
            float po = pre[(ghj + 384) * 4 + gm];
            float ig = sigmoidf_(pi), fg = sigmoidf_(pf);
            float gg = tanhf_(pg), og = sigmoidf_(po);
            c0 = fmaf(fg, c0, ig * gg);
            float h = og * tanhf_(c0);
            h_lds[ghj * 4 + gm] = h;
            if (store_h) h1c[((b0 + gm) * TC + tt) * HH + ghj] = h;
        }
        {
            float pi = pre[(ghj)*4 + gm + 2];
            float pf = pre[(ghj + 128) * 4 + gm + 2];
            float pg = pre[(ghj + 256) * 4 + gm + 2];
            float po = pre[(ghj + 384) * 4 + gm + 2];
            float ig = sigmoidf_(pi), fg = sigmoidf_(pf);
            float gg = tanhf_(pg), og = sigmoidf_(po);
            c1 = fmaf(fg, c1, ig * gg);
            float h = og * tanhf_(c1);
            h_lds[ghj * 4 + gm + 2] = h;
            if (store_h) h1c[((b0 + gm + 2) * TC + tt) * HH + ghj] = h;
        }
        __syncthreads();
    }

    cs[(b0 + gm) * HH + ghj] = c0;
    cs[(b0 + gm + 2) * HH + ghj] = c1;
    hs[(b0 + gm) * HH + ghj] = h_lds[ghj * 4 + gm];
    hs[(b0 + gm + 2) * HH + ghj] = h_lds[ghj * 4 + gm + 2];
}

// ---------------- in-projection GEMM: xp[r][512] = in[row(r)][K] @ W^T + b ---
// 256 threads; thread t owns columns t, t+256 (W rows in regs); 8-row tiles.
template <int K>
__global__ __launch_bounds__(256, 1) void inproj_kernel(
    const float* __restrict__ in, const float* __restrict__ Wih,
    const float* __restrict__ bih, const float* __restrict__ bhh,
    float* __restrict__ xp, int rpb, int tcshift, int tcmask, int Tstride, int t0)
{
    const int t = threadIdx.x;
    const int blk = blockIdx.x;

    float wA[K], wB[K];
#pragma unroll
    for (int q = 0; q < K / 4; ++q)
        *(float4*)&wA[4 * q] = *(const float4*)&Wih[(long)t * K + 4 * q];
#pragma unroll
    for (int q = 0; q < K / 4; ++q)
        *(float4*)&wB[4 * q] = *(const float4*)&Wih[(long)(t + 256) * K + 4 * q];
    const float bsA = bih[t] + bhh[t];
    const float bsB = bih[t + 256] + bhh[t + 256];

    __shared__ __align__(16) float hl[K * 8];  // [k][m]

    const long r0b = (long)blk * rpb;

    for (int tile = 0; tile < rpb / 8; ++tile) {
        const long r0 = r0b + tile * 8;
        __syncthreads();
        // stage 8 rows x K, coalesced over k
#pragma unroll
        for (int p = 0; p < (8 * K) / 256; ++p) {
            int e = t + p * 256;
            int k = e & (K - 1), m = e >> (K == 128 ? 7 : 6);
            long r = r0 + m;
            long b = r >> tcshift, tloc = r & tcmask;
            hl[k * 8 + m] = in[(b * Tstride + t0 + tloc) * K + k];
        }
        __syncthreads();

        v2f accA[4], accB[4];
#pragma unroll
        for (int m = 0; m < 4; ++m) {
            accA[m].x = bsA; accA[m].y = bsA;
            accB[m].x = bsB; accB[m].y = bsB;
        }
#pragma unroll
        for (int k = 0; k < K; ++k) {
            float4 v0 = *(const float4*)&hl[k * 8];
            float4 v1 = *(const float4*)&hl[k * 8 + 4];
            v2f wa; wa.x = wA[k]; wa.y = wA[k];
            v2f wb; wb.x = wB[k]; wb.y = wB[k];
            v2f p01; p01.x = v0.x; p01.y = v0.y;
            v2f p23; p23.x = v0.z; p23.y = v0.w;
            v2f p45; p45.x = v1.x; p45.y = v1.y;
            v2f p67; p67.x = v1.z; p67.y = v1.w;
            accA[0] = pkfma(wa, p01, accA[0]);
            accA[1] = pkfma(wa, p23, accA[1]);
            accA[2] = pkfma(wa, p45, accA[2]);
            accA[3] = pkfma(wa, p67, accA[3]);
            accB[0] = pkfma(wb, p01, accB[0]);
            accB[1] = pkfma(wb, p23, accB[1]);
            accB[2] = pkfma(wb, p45, accB[2]);
            accB[3] = pkfma(wb, p67, accB[3]);
        }
        const float aflat[8] = {accA[0].x, accA[0].y, accA[1].x, accA[1].y,
                                accA[2].x, accA[2].y, accA[3].x, accA[3].y};
        const float bflat[8] = {accB[0].x, accB[0].y, accB[1].x, accB[1].y,
                                accB[2].x, accB[2].y, accB[3].x, accB[3].y};
#pragma unroll
        for (int m = 0; m < 8; ++m) {
            xp[(r0 + m) * GG + t] = aflat[m];
            xp[(r0 + m) * GG + t + 256] = bflat[m];
        }
    }
}

// ---------------- FC head ---------------------------------------------------
__global__ __launch_bounds__(64) void head_kernel(
    const float* __restrict__ h, const float* __restrict__ w1,
    const float* __restrict__ b1, const float* __restrict__ w2,
    const float* __restrict__ b2, float* __restrict__ out)
{
    const int b = blockIdx.x;
    const int n = threadIdx.x;
    float acc = b1[n];
#pragma unroll
    for (int k = 0; k < HH; ++k)
        acc = fmaf(w1[n * HH + k], h[b * HH + k], acc);
    float v = fmaxf(acc, 0.0f) * w2[n];
#pragma unroll
    for (int off = 32; off > 0; off >>= 1)
        v += __shfl_down(v, off);
    if (n == 0) out[b] = v + b2[0];
}

extern "C" void kernel_launch(void* const* d_in, const int* in_sizes, int n_in,
                              void* d_out, int out_size, void* d_ws, size_t ws_size,
                              hipStream_t stream)
{
    const float* x    = (const float*)d_in[0];
    const float* Wih0 = (const float*)d_in[1];
    const float* Whh0 = (const float*)d_in[2];
    const float* bih0 = (const float*)d_in[3];
    const float* bhh0 = (const float*)d_in[4];
    const float* Wih1 = (const float*)d_in[5];
    const float* Whh1 = (const float*)d_in[6];
    const float* bih1 = (const float*)d_in[7];
    const float* bhh1 = (const float*)d_in[8];
    const float* w1   = (const float*)d_in[9];
    const float* b1   = (const float*)d_in[10];
    const float* w2   = (const float*)d_in[11];
    const float* b2   = (const float*)d_in[12];
    float* out = (float*)d_out;

    // workspace: xp0 [B*TC][512], xp1 [B*TC][512], h1c [B*TC][128], 4 state bufs
    const size_t sz_state = (size_t)BB * HH * 4;
    int TC = 2;
    const int cands[6] = {64, 32, 16, 8, 4, 2};
    for (int i = 0; i < 6; ++i) {
        size_t need = (size_t)BB * cands[i] * (GG + GG + HH) * 4 + 4 * sz_state;
        if (need <= ws_size) { TC = cands[i]; break; }
    }
    int tcshift = 0; while ((1 << tcshift) < TC) ++tcshift;
    const int tcmask = TC - 1;

    char* ws = (char*)d_ws;
    float* xp0 = (float*)ws;
    float* xp1 = xp0 + (size_t)BB * TC * GG;
    float* h1c = xp1 + (size_t)BB * TC * GG;
    float* hs0 = h1c + (size_t)BB * TC * HH;
    float* cs0 = hs0 + (size_t)BB * HH;
    float* hs1 = cs0 + (size_t)BB * HH;
    float* cs1 = hs1 + (size_t)BB * HH;

    hipMemsetAsync(hs0, 0, 4 * sz_state, stream);

    const int rpb = 4 * TC;  // rows per gemm block (B*TC/256)

    for (int t0 = 0; t0 < TT; t0 += TC) {
        inproj_kernel<FF><<<256, 256, 0, stream>>>(
            x, Wih0, bih0, bhh0, xp0, rpb, tcshift, tcmask, TT, t0);
        rec_kernel<<<256, 256, 0, stream>>>(xp0, Whh0, hs0, cs0, h1c, TC, 1);
        inproj_kernel<HH><<<256, 256, 0, stream>>>(
            h1c, Wih1, bih1, bhh1, xp1, rpb, tcshift, tcmask, TC, 0);
        rec_kernel<<<256, 256, 0, stream>>>(xp1, Whh1, hs1, cs1, (float*)nullptr, TC, 0);
    }
    head_kernel<<<BB, 64, 0, stream>>>(hs1, w1, b1, w2, b2, out);
}

// Round 4
// 2098.321 us; speedup vs baseline: 5.6830x; 5.6830x over previous
//
#include <hip/hip_runtime.h>
#include <math.h>

// 2-layer LSTM (B=1024,T=512,F=64,H=128) + FC head.
// R4: full MFMA rewrite. 64 blocks x 512 thr (8 waves); block owns 16 batch
// rows; wave owns 16 hidden units (4 gate-tiles of 16 cols, N=64).
// Weights as B-fragments in VGPRs: fp16 for recurrent matrices, split-bf16
// (hi+lo, 3-term MFMA) for the x-projection. h exchanged across waves via
// double-buffered LDS (1 barrier/step). x / h1 A-frags loaded from global
// with distance-1 prefetch. c-state, gates all in registers (MFMA C-layout
// keeps i,f,g,o for one (row,hidden) in one lane). 3 dispatches total.
//
// MFMA 16x16x32 layouts (gfx950, verified refs in guide):
//   A: m = lane&15, k = (lane>>4)*8 + j   (j=0..7)
//   B: n = lane&15, k = (lane>>4)*8 + j
//   C/D: col = lane&15, row = (lane>>4)*4 + r  (r=0..3)

#define BB 1024
#define TT 512
#define FF 64
#define HH 128

typedef __attribute__((ext_vector_type(8))) short     v8s;  // 8 x bf16
typedef __attribute__((ext_vector_type(8))) _Float16  v8h;  // 8 x fp16
typedef __attribute__((ext_vector_type(4))) float     v4f;

__device__ __forceinline__ float sigmoidf_(float x) {
    return 1.0f / (1.0f + __expf(-x));
}
__device__ __forceinline__ float tanhf_(float x) {
    return 1.0f - 2.0f / (1.0f + __expf(2.0f * x));
}
__device__ __forceinline__ short bf16r(float v) {  // RNE fp32->bf16
    unsigned u = __float_as_uint(v);
    return (short)((u + 0x7FFFu + ((u >> 16) & 1u)) >> 16);
}
__device__ __forceinline__ float bf16tof(short s) {
    return __uint_as_float(((unsigned)(unsigned short)s) << 16);
}

// ---------------- Layer 0: fused x-proj (split-bf16) + recurrence (fp16) ----
__global__ __launch_bounds__(512, 2) void rec0_kernel(
    const float* __restrict__ x, const float* __restrict__ Wih,
    const float* __restrict__ Whh, const float* __restrict__ bih,
    const float* __restrict__ bhh, _Float16* __restrict__ h1c)
{
    const int tid = threadIdx.x;
    const int w = tid >> 6;          // wave 0..7 -> hidden [16w,16w+16)
    const int l = tid & 63;
    const int lane16 = l & 15;
    const int quad = l >> 4;
    const int jh = 16 * w + lane16;  // this lane's hidden unit (cols)
    const long b0 = (long)blockIdx.x * 16;

    v8h bh[4][4];                 // Whh fp16 B-frags [gate][ktile]
    v8s bxh[4][2], bxl[4][2];     // Wih split-bf16 B-frags
    float bias[4];
    float c[4] = {0.f, 0.f, 0.f, 0.f};

#pragma unroll
    for (int g = 0; g < 4; ++g) {
        const int col = g * 128 + jh;
        bias[g] = bih[col] + bhh[col];
#pragma unroll
        for (int q = 0; q < 4; ++q) {
            const float* p = &Whh[(long)col * HH + q * 32 + quad * 8];
            float4 u0 = *(const float4*)p;
            float4 u1 = *(const float4*)(p + 4);
            v8h t;
            t[0]=(_Float16)u0.x; t[1]=(_Float16)u0.y; t[2]=(_Float16)u0.z; t[3]=(_Float16)u0.w;
            t[4]=(_Float16)u1.x; t[5]=(_Float16)u1.y; t[6]=(_Float16)u1.z; t[7]=(_Float16)u1.w;
            bh[g][q] = t;
        }
#pragma unroll
        for (int q = 0; q < 2; ++q) {
            const float* p = &Wih[(long)col * FF + q * 32 + quad * 8];
            float4 u0 = *(const float4*)p;
            float4 u1 = *(const float4*)(p + 4);
            float vv[8] = {u0.x,u0.y,u0.z,u0.w,u1.x,u1.y,u1.z,u1.w};
            v8s hi, lo;
#pragma unroll
            for (int e = 0; e < 8; ++e) {
                short hbits = bf16r(vv[e]);
                hi[e] = hbits;
                lo[e] = bf16r(vv[e] - bf16tof(hbits));
            }
            bxh[g][q] = hi; bxl[g][q] = lo;
        }
    }

    // h exchange: [buf][m][136] halfs (pad 136: 16B-aligned rows, 2-way banks)
    __shared__ _Float16 hbuf[2][16 * 136];
    for (int i = tid; i < 16 * 136; i += 512) hbuf[0][i] = (_Float16)0.0f;

    // preload x A-frag source for t=0 (lane16 = batch row m)
    float4 xv[2][2];
    {
        const float* px = &x[((b0 + lane16) * TT + 0) * FF + quad * 8];
        xv[0][0] = *(const float4*)px;        xv[0][1] = *(const float4*)(px + 4);
        xv[1][0] = *(const float4*)(px + 32); xv[1][1] = *(const float4*)(px + 36);
    }
    __syncthreads();

    for (int t = 0; t < TT; ++t) {
        const int cur = t & 1, nxt = cur ^ 1;

        // build split-bf16 x A-frags for this step
        v8s xh[2], xl[2];
#pragma unroll
        for (int q = 0; q < 2; ++q) {
            float vv[8] = {xv[q][0].x, xv[q][0].y, xv[q][0].z, xv[q][0].w,
                           xv[q][1].x, xv[q][1].y, xv[q][1].z, xv[q][1].w};
#pragma unroll
            for (int e = 0; e < 8; ++e) {
                short hbits = bf16r(vv[e]);
                xh[q][e] = hbits;
                xl[q][e] = bf16r(vv[e] - bf16tof(hbits));
            }
        }
        // prefetch next step's x
        {
            const int tn = (t < TT - 1) ? t + 1 : t;
            const float* px = &x[((b0 + lane16) * TT + tn) * FF + quad * 8];
            xv[0][0] = *(const float4*)px;        xv[0][1] = *(const float4*)(px + 4);
            xv[1][0] = *(const float4*)(px + 32); xv[1][1] = *(const float4*)(px + 36);
        }
        // h A-frags from LDS
        v8h ah[4];
#pragma unroll
        for (int q = 0; q < 4; ++q)
            ah[q] = *(const v8h*)&hbuf[cur][lane16 * 136 + q * 32 + quad * 8];

        v4f acc[4];
#pragma unroll
        for (int g = 0; g < 4; ++g) {
            v4f a = {bias[g], bias[g], bias[g], bias[g]};
            a = __builtin_amdgcn_mfma_f32_16x16x32_bf16(xh[0], bxh[g][0], a, 0, 0, 0);
            a = __builtin_amdgcn_mfma_f32_16x16x32_bf16(xh[0], bxl[g][0], a, 0, 0, 0);
            a = __builtin_amdgcn_mfma_f32_16x16x32_bf16(xl[0], bxh[g][0], a, 0, 0, 0);
            a = __builtin_amdgcn_mfma_f32_16x16x32_bf16(xh[1], bxh[g][1], a, 0, 0, 0);
            a = __builtin_amdgcn_mfma_f32_16x16x32_bf16(xh[1], bxl[g][1], a, 0, 0, 0);
            a = __builtin_amdgcn_mfma_f32_16x16x32_bf16(xl[1], bxh[g][1], a, 0, 0, 0);
#pragma unroll
            for (int q = 0; q < 4; ++q)
                a = __builtin_amdgcn_mfma_f32_16x16x32_f16(ah[q], bh[g][q], a, 0, 0, 0);
            acc[g] = a;
        }

#pragma unroll
        for (int r = 0; r < 4; ++r) {
            float ig = sigmoidf_(acc[0][r]);
            float fg = sigmoidf_(acc[1][r]);
            float gg = tanhf_(acc[2][r]);
            float og = sigmoidf_(acc[3][r]);
            c[r] = fmaf(fg, c[r], ig * gg);
            float h = og * tanhf_(c[r]);
            const int m = quad * 4 + r;
            const _Float16 hh = (_Float16)h;
            h1c[((b0 + m) * TT + t) * HH + jh] = hh;
            hbuf[nxt][m * 136 + jh] = hh;
        }
        __syncthreads();
    }
}

// ---------------- Layer 1: fused h1-proj + recurrence (both fp16) -----------
__global__ __launch_bounds__(512, 2) void rec1_kernel(
    const _Float16* __restrict__ h1c, const float* __restrict__ Wih,
    const float* __restrict__ Whh, const float* __restrict__ bih,
    const float* __restrict__ bhh, float* __restrict__ hs)
{
    const int tid = threadIdx.x;
    const int w = tid >> 6;
    const int l = tid & 63;
    const int lane16 = l & 15;
    const int quad = l >> 4;
    const int jh = 16 * w + lane16;
    const long b0 = (long)blockIdx.x * 16;

    v8h bi[4][4], bh[4][4];
    float bias[4];
    float c[4] = {0.f, 0.f, 0.f, 0.f};

#pragma unroll
    for (int g = 0; g < 4; ++g) {
        const int col = g * 128 + jh;
        bias[g] = bih[col] + bhh[col];
#pragma unroll
        for (int q = 0; q < 4; ++q) {
            const float* pi = &Wih[(long)col * HH + q * 32 + quad * 8];
            float4 u0 = *(const float4*)pi;
            float4 u1 = *(const float4*)(pi + 4);
            v8h t;
            t[0]=(_Float16)u0.x; t[1]=(_Float16)u0.y; t[2]=(_Float16)u0.z; t[3]=(_Float16)u0.w;
            t[4]=(_Float16)u1.x; t[5]=(_Float16)u1.y; t[6]=(_Float16)u1.z; t[7]=(_Float16)u1.w;
            bi[g][q] = t;
            const float* ph = &Whh[(long)col * HH + q * 32 + quad * 8];
            float4 v0 = *(const float4*)ph;
            float4 v1 = *(const float4*)(ph + 4);
            v8h s;
            s[0]=(_Float16)v0.x; s[1]=(_Float16)v0.y; s[2]=(_Float16)v0.z; s[3]=(_Float16)v0.w;
            s[4]=(_Float16)v1.x; s[5]=(_Float16)v1.y; s[6]=(_Float16)v1.z; s[7]=(_Float16)v1.w;
            bh[g][q] = s;
        }
    }

    __shared__ _Float16 hbuf[2][16 * 136];
    for (int i = tid; i < 16 * 136; i += 512) hbuf[0][i] = (_Float16)0.0f;

    // preload h1 A-frags for t=0 (already fp16 in h1c)
    v8h a1[4];
#pragma unroll
    for (int q = 0; q < 4; ++q)
        a1[q] = *(const v8h*)&h1c[((b0 + lane16) * TT + 0) * HH + q * 32 + quad * 8];
    __syncthreads();

    for (int t = 0; t < TT; ++t) {
        const int cur = t & 1, nxt = cur ^ 1;

        // h2 A-frags from LDS
        v8h a2[4];
#pragma unroll
        for (int q = 0; q < 4; ++q)
            a2[q] = *(const v8h*)&hbuf[cur][lane16 * 136 + q * 32 + quad * 8];

        // prefetch next step's h1
        v8h a1n[4];
        {
            const int tn = (t < TT - 1) ? t + 1 : t;
#pragma unroll
            for (int q = 0; q < 4; ++q)
                a1n[q] = *(const v8h*)&h1c[((b0 + lane16) * TT + tn) * HH + q * 32 + quad * 8];
        }

        v4f acc[4];
#pragma unroll
        for (int g = 0; g < 4; ++g) {
            v4f a = {bias[g], bias[g], bias[g], bias[g]};
#pragma unroll
            for (int q = 0; q < 4; ++q)
                a = __builtin_amdgcn_mfma_f32_16x16x32_f16(a1[q], bi[g][q], a, 0, 0, 0);
#pragma unroll
            for (int q = 0; q < 4; ++q)
                a = __builtin_amdgcn_mfma_f32_16x16x32_f16(a2[q], bh[g][q], a, 0, 0, 0);
            acc[g] = a;
        }

#pragma unroll
        for (int r = 0; r < 4; ++r) {
            float ig = sigmoidf_(acc[0][r]);
            float fg = sigmoidf_(acc[1][r]);
            float gg = tanhf_(acc[2][r]);
            float og = sigmoidf_(acc[3][r]);
            c[r] = fmaf(fg, c[r], ig * gg);
            float h = og * tanhf_(c[r]);
            const int m = quad * 4 + r;
            hbuf[nxt][m * 136 + jh] = (_Float16)h;
            if (t == TT - 1) hs[(b0 + m) * HH + jh] = h;
        }
        __syncthreads();

#pragma unroll
        for (int q = 0; q < 4; ++q) a1[q] = a1n[q];
    }
}

// ---------------- FC head: out = relu(h @ fc1^T + b1) @ fc2^T + b2 ----------
__global__ __launch_bounds__(64) void head_kernel(
    const float* __restrict__ h, const float* __restrict__ w1,
    const float* __restrict__ b1, const float* __restrict__ w2,
    const float* __restrict__ b2, float* __restrict__ out)
{
    const int b = blockIdx.x;
    const int n = threadIdx.x;
    float acc = b1[n];
#pragma unroll
    for (int k = 0; k < HH; ++k)
        acc = fmaf(w1[n * HH + k], h[b * HH + k], acc);
    float v = fmaxf(acc, 0.0f) * w2[n];
#pragma unroll
    for (int off = 32; off > 0; off >>= 1)
        v += __shfl_down(v, off);
    if (n == 0) out[b] = v + b2[0];
}

extern "C" void kernel_launch(void* const* d_in, const int* in_sizes, int n_in,
                              void* d_out, int out_size, void* d_ws, size_t ws_size,
                              hipStream_t stream)
{
    const float* x    = (const float*)d_in[0];
    const float* Wih0 = (const float*)d_in[1];
    const float* Whh0 = (const float*)d_in[2];
    const float* bih0 = (const float*)d_in[3];
    const float* bhh0 = (const float*)d_in[4];
    const float* Wih1 = (const float*)d_in[5];
    const float* Whh1 = (const float*)d_in[6];
    const float* bih1 = (const float*)d_in[7];
    const float* bhh1 = (const float*)d_in[8];
    const float* w1   = (const float*)d_in[9];
    const float* b1   = (const float*)d_in[10];
    const float* w2   = (const float*)d_in[11];
    const float* b2   = (const float*)d_in[12];
    float* out = (float*)d_out;

    _Float16* h1c = (_Float16*)d_ws;                                   // 134 MB
    float* hs = (float*)((char*)d_ws + (size_t)BB * TT * HH * sizeof(_Float16));

    rec0_kernel<<<64, 512, 0, stream>>>(x, Wih0, Whh0, bih0, bhh0, h1c);
    rec1_kernel<<<64, 512, 0, stream>>>(h1c, Wih1, Whh1, bih1, bhh1, hs);
    head_kernel<<<BB, 64, 0, stream>>>(hs, w1, b1, w2, b2, out);
}

// Round 5
// 1358.179 us; speedup vs baseline: 8.7799x; 1.5450x over previous
//
#include <hip/hip_runtime.h>
#include <math.h>

// 2-layer LSTM (B=1024,T=512,F=64,H=128) + FC head.
// R5: layer-pipelined fused kernel. Blocks 0-63 = layer0 (R4 rec0 math),
// blocks 64-127 = layer1 (R4 rec1 math), overlapped producer->consumer via
// device-scope flags (publish every 8 steps: full __syncthreads drains all
// waves' h1c stores, then release-store flag; consumer acquire-polls, lags
// <=16 steps). All other steps use a LIGHT barrier (lgkmcnt only, no vmcnt
// drain) -- removes the ~400-900 cyc/step store/load drain R4 paid at every
// __syncthreads. 128 blocks <= 256 CUs => all co-resident; producers never
// wait on consumers => no deadlock; spin is iteration-bounded.

#define BB 1024
#define TT 512
#define FF 64
#define HH 128

typedef __attribute__((ext_vector_type(8))) short     v8s;  // 8 x bf16
typedef __attribute__((ext_vector_type(8))) _Float16  v8h;  // 8 x fp16
typedef __attribute__((ext_vector_type(4))) float     v4f;

__device__ __forceinline__ float sigmoidf_(float x) {
    return 1.0f / (1.0f + __expf(-x));
}
__device__ __forceinline__ float tanhf_(float x) {
    return 1.0f - 2.0f / (1.0f + __expf(2.0f * x));
}
__device__ __forceinline__ short bf16r(float v) {  // RNE fp32->bf16
    unsigned u = __float_as_uint(v);
    return (short)((u + 0x7FFFu + ((u >> 16) & 1u)) >> 16);
}
__device__ __forceinline__ float bf16tof(short s) {
    return __uint_as_float(((unsigned)(unsigned short)s) << 16);
}
// Barrier WITHOUT the compiler's vmcnt(0) drain (LDS ordering only).
__device__ __forceinline__ void light_barrier() {
    asm volatile("s_waitcnt lgkmcnt(0)\n\ts_barrier" ::: "memory");
}
// Bounded acquire-poll on a device-scope flag (RMW -> always coherent).
__device__ __forceinline__ void wait_flag_ge(int* f, int need) {
    for (int i = 0; i < 2000000; ++i) {
        int v = __hip_atomic_fetch_add(f, 0, __ATOMIC_ACQUIRE,
                                       __HIP_MEMORY_SCOPE_AGENT);
        if (v >= need) return;
        __builtin_amdgcn_s_sleep(4);
    }
}

// MFMA 16x16x32 layouts: A/B: m(n)=lane&15, k=(lane>>4)*8+j ; C/D: col=lane&15,
// row=(lane>>4)*4+r.

__global__ __launch_bounds__(512, 2) void fused_lstm_kernel(
    const float* __restrict__ x,
    const float* __restrict__ Wih0, const float* __restrict__ Whh0,
    const float* __restrict__ bih0, const float* __restrict__ bhh0,
    const float* __restrict__ Wih1, const float* __restrict__ Whh1,
    const float* __restrict__ bih1, const float* __restrict__ bhh1,
    _Float16* __restrict__ h1c, float* __restrict__ hs, int* __restrict__ flags)
{
    const int tid = threadIdx.x;
    const int w = tid >> 6;
    const int l = tid & 63;
    const int lane16 = l & 15;
    const int quad = l >> 4;
    const int jh = 16 * w + lane16;

    __shared__ _Float16 hbuf[2][16 * 136];

    if (blockIdx.x < 64) {
        // ================= LAYER 0 (producer) =================
        const int tile = blockIdx.x;
        const long b0 = (long)tile * 16;
        int* flagp = &flags[tile];

        v8h bh[4][4];                 // Whh0 fp16 B-frags
        v8s bxh[4][2], bxl[4][2];     // Wih0 split-bf16 B-frags
        float bias[4];
        float c[4] = {0.f, 0.f, 0.f, 0.f};

#pragma unroll
        for (int g = 0; g < 4; ++g) {
            const int col = g * 128 + jh;
            bias[g] = bih0[col] + bhh0[col];
#pragma unroll
            for (int q = 0; q < 4; ++q) {
                const float* p = &Whh0[(long)col * HH + q * 32 + quad * 8];
                float4 u0 = *(const float4*)p;
                float4 u1 = *(const float4*)(p + 4);
                v8h t;
                t[0]=(_Float16)u0.x; t[1]=(_Float16)u0.y; t[2]=(_Float16)u0.z; t[3]=(_Float16)u0.w;
                t[4]=(_Float16)u1.x; t[5]=(_Float16)u1.y; t[6]=(_Float16)u1.z; t[7]=(_Float16)u1.w;
                bh[g][q] = t;
            }
#pragma unroll
            for (int q = 0; q < 2; ++q) {
                const float* p = &Wih0[(long)col * FF + q * 32 + quad * 8];
                float4 u0 = *(const float4*)p;
                float4 u1 = *(const float4*)(p + 4);
                float vv[8] = {u0.x,u0.y,u0.z,u0.w,u1.x,u1.y,u1.z,u1.w};
                v8s hi, lo;
#pragma unroll
                for (int e = 0; e < 8; ++e) {
                    short hbits = bf16r(vv[e]);
                    hi[e] = hbits;
                    lo[e] = bf16r(vv[e] - bf16tof(hbits));
                }
                bxh[g][q] = hi; bxl[g][q] = lo;
            }
        }

        for (int i = tid; i < 16 * 136; i += 512) hbuf[0][i] = (_Float16)0.0f;

        float4 xv[2][2];
        {
            const float* px = &x[((b0 + lane16) * TT + 0) * FF + quad * 8];
            xv[0][0] = *(const float4*)px;        xv[0][1] = *(const float4*)(px + 4);
            xv[1][0] = *(const float4*)(px + 32); xv[1][1] = *(const float4*)(px + 36);
        }
        __syncthreads();

        for (int t = 0; t < TT; ++t) {
            const int cur = t & 1, nxt = cur ^ 1;

            v8s xh[2], xl[2];
#pragma unroll
            for (int q = 0; q < 2; ++q) {
                float vv[8] = {xv[q][0].x, xv[q][0].y, xv[q][0].z, xv[q][0].w,
                               xv[q][1].x, xv[q][1].y, xv[q][1].z, xv[q][1].w};
#pragma unroll
                for (int e = 0; e < 8; ++e) {
                    short hbits = bf16r(vv[e]);
                    xh[q][e] = hbits;
                    xl[q][e] = bf16r(vv[e] - bf16tof(hbits));
                }
            }
            {
                const int tn = (t < TT - 1) ? t + 1 : t;
                const float* px = &x[((b0 + lane16) * TT + tn) * FF + quad * 8];
                xv[0][0] = *(const float4*)px;        xv[0][1] = *(const float4*)(px + 4);
                xv[1][0] = *(const float4*)(px + 32); xv[1][1] = *(const float4*)(px + 36);
            }
            v8h ah[4];
#pragma unroll
            for (int q = 0; q < 4; ++q)
                ah[q] = *(const v8h*)&hbuf[cur][lane16 * 136 + q * 32 + quad * 8];

            v4f acc[4];
#pragma unroll
            for (int g = 0; g < 4; ++g) {
                v4f a = {bias[g], bias[g], bias[g], bias[g]};
                a = __builtin_amdgcn_mfma_f32_16x16x32_bf16(xh[0], bxh[g][0], a, 0, 0, 0);
                a = __builtin_amdgcn_mfma_f32_16x16x32_bf16(xh[0], bxl[g][0], a, 0, 0, 0);
                a = __builtin_amdgcn_mfma_f32_16x16x32_bf16(xl[0], bxh[g][0], a, 0, 0, 0);
                a = __builtin_amdgcn_mfma_f32_16x16x32_bf16(xh[1], bxh[g][1], a, 0, 0, 0);
                a = __builtin_amdgcn_mfma_f32_16x16x32_bf16(xh[1], bxl[g][1], a, 0, 0, 0);
                a = __builtin_amdgcn_mfma_f32_16x16x32_bf16(xl[1], bxh[g][1], a, 0, 0, 0);
#pragma unroll
                for (int q = 0; q < 4; ++q)
                    a = __builtin_amdgcn_mfma_f32_16x16x32_f16(ah[q], bh[g][q], a, 0, 0, 0);
                acc[g] = a;
            }

#pragma unroll
            for (int r = 0; r < 4; ++r) {
                float ig = sigmoidf_(acc[0][r]);
                float fg = sigmoidf_(acc[1][r]);
                float gg = tanhf_(acc[2][r]);
                float og = sigmoidf_(acc[3][r]);
                c[r] = fmaf(fg, c[r], ig * gg);
                float h = og * tanhf_(c[r]);
                const int m = quad * 4 + r;
                const _Float16 hh = (_Float16)h;
                h1c[((b0 + m) * TT + t) * HH + jh] = hh;
                hbuf[nxt][m * 136 + jh] = hh;
            }

            if ((t & 7) == 7) {
                __syncthreads();  // drains every wave's h1c stores (vmcnt 0)
                if (tid == 0)
                    __hip_atomic_store(flagp, t + 1, __ATOMIC_RELEASE,
                                       __HIP_MEMORY_SCOPE_AGENT);
            } else {
                light_barrier();
            }
        }
    } else {
        // ================= LAYER 1 (consumer) =================
        const int tile = blockIdx.x - 64;
        const long b0 = (long)tile * 16;
        int* flagp = &flags[tile];

        v8h bi[4][4], bh[4][4];
        float bias[4];
        float c[4] = {0.f, 0.f, 0.f, 0.f};

#pragma unroll
        for (int g = 0; g < 4; ++g) {
            const int col = g * 128 + jh;
            bias[g] = bih1[col] + bhh1[col];
#pragma unroll
            for (int q = 0; q < 4; ++q) {
                const float* pi = &Wih1[(long)col * HH + q * 32 + quad * 8];
                float4 u0 = *(const float4*)pi;
                float4 u1 = *(const float4*)(pi + 4);
                v8h t;
                t[0]=(_Float16)u0.x; t[1]=(_Float16)u0.y; t[2]=(_Float16)u0.z; t[3]=(_Float16)u0.w;
                t[4]=(_Float16)u1.x; t[5]=(_Float16)u1.y; t[6]=(_Float16)u1.z; t[7]=(_Float16)u1.w;
                bi[g][q] = t;
                const float* ph = &Whh1[(long)col * HH + q * 32 + quad * 8];
                float4 v0 = *(const float4*)ph;
                float4 v1 = *(const float4*)(ph + 4);
                v8h s;
                s[0]=(_Float16)v0.x; s[1]=(_Float16)v0.y; s[2]=(_Float16)v0.z; s[3]=(_Float16)v0.w;
                s[4]=(_Float16)v1.x; s[5]=(_Float16)v1.y; s[6]=(_Float16)v1.z; s[7]=(_Float16)v1.w;
                bh[g][q] = s;
            }
        }

        for (int i = tid; i < 16 * 136; i += 512) hbuf[0][i] = (_Float16)0.0f;

        // wait for h1[0..15] before the t=0 preload (covers prefetch to t=8)
        if (tid == 0) wait_flag_ge(flagp, 16);
        __syncthreads();

        v8h a1[4];
#pragma unroll
        for (int q = 0; q < 4; ++q)
            a1[q] = *(const v8h*)&h1c[((b0 + lane16) * TT + 0) * HH + q * 32 + quad * 8];

        for (int t = 0; t < TT; ++t) {
            if ((t & 7) == 0 && t > 0) {
                if (tid == 0) wait_flag_ge(flagp, (t + 16 < TT) ? t + 16 : TT);
                light_barrier();
            }
            const int cur = t & 1, nxt = cur ^ 1;

            v8h a2[4];
#pragma unroll
            for (int q = 0; q < 4; ++q)
                a2[q] = *(const v8h*)&hbuf[cur][lane16 * 136 + q * 32 + quad * 8];

            v8h a1n[4];
            {
                const int tn = (t < TT - 1) ? t + 1 : t;
#pragma unroll
                for (int q = 0; q < 4; ++q)
                    a1n[q] = *(const v8h*)&h1c[((b0 + lane16) * TT + tn) * HH + q * 32 + quad * 8];
            }

            v4f acc[4];
#pragma unroll
            for (int g = 0; g < 4; ++g) {
                v4f a = {bias[g], bias[g], bias[g], bias[g]};
#pragma unroll
                for (int q = 0; q < 4; ++q)
                    a = __builtin_amdgcn_mfma_f32_16x16x32_f16(a1[q], bi[g][q], a, 0, 0, 0);
#pragma unroll
                for (int q = 0; q < 4; ++q)
                    a = __builtin_amdgcn_mfma_f32_16x16x32_f16(a2[q], bh[g][q], a, 0, 0, 0);
                acc[g] = a;
            }

#pragma unroll
            for (int r = 0; r < 4; ++r) {
                float ig = sigmoidf_(acc[0][r]);
                float fg = sigmoidf_(acc[1][r]);
                float gg = tanhf_(acc[2][r]);
                float og = sigmoidf_(acc[3][r]);
                c[r] = fmaf(fg, c[r], ig * gg);
                float h = og * tanhf_(c[r]);
                const int m = quad * 4 + r;
                hbuf[nxt][m * 136 + jh] = (_Float16)h;
                if (t == TT - 1) hs[(b0 + m) * HH + jh] = h;
            }
            light_barrier();

#pragma unroll
            for (int q = 0; q < 4; ++q) a1[q] = a1n[q];
        }
    }
}

// ---------------- FC head: out = relu(h @ fc1^T + b1) @ fc2^T + b2 ----------
__global__ __launch_bounds__(64) void head_kernel(
    const float* __restrict__ h, const float* __restrict__ w1,
    const float* __restrict__ b1, const float* __restrict__ w2,
    const float* __restrict__ b2, float* __restrict__ out)
{
    const int b = blockIdx.x;
    const int n = threadIdx.x;
    float acc = b1[n];
#pragma unroll
    for (int k = 0; k < HH; ++k)
        acc = fmaf(w1[n * HH + k], h[b * HH + k], acc);
    float v = fmaxf(acc, 0.0f) * w2[n];
#pragma unroll
    for (int off = 32; off > 0; off >>= 1)
        v += __shfl_down(v, off);
    if (n == 0) out[b] = v + b2[0];
}

extern "C" void kernel_launch(void* const* d_in, const int* in_sizes, int n_in,
                              void* d_out, int out_size, void* d_ws, size_t ws_size,
                              hipStream_t stream)
{
    const float* x    = (const float*)d_in[0];
    const float* Wih0 = (const float*)d_in[1];
    const float* Whh0 = (const float*)d_in[2];
    const float* bih0 = (const float*)d_in[3];
    const float* bhh0 = (const float*)d_in[4];
    const float* Wih1 = (const float*)d_in[5];
    const float* Whh1 = (const float*)d_in[6];
    const float* bih1 = (const float*)d_in[7];
    const float* bhh1 = (const float*)d_in[8];
    const float* w1   = (const float*)d_in[9];
    const float* b1   = (const float*)d_in[10];
    const float* w2   = (const float*)d_in[11];
    const float* b2   = (const float*)d_in[12];
    float* out = (float*)d_out;

    char* ws = (char*)d_ws;
    _Float16* h1c = (_Float16*)ws;                              // 134 MB
    float* hs  = (float*)(ws + (size_t)BB * TT * HH * sizeof(_Float16));
    int* flags = (int*)(ws + (size_t)BB * TT * HH * sizeof(_Float16)
                           + (size_t)BB * HH * sizeof(float));

    hipMemsetAsync(flags, 0, 64 * sizeof(int), stream);

    fused_lstm_kernel<<<128, 512, 0, stream>>>(
        x, Wih0, Whh0, bih0, bhh0, Wih1, Whh1, bih1, bhh1, h1c, hs, flags);
    head_kernel<<<BB, 64, 0, stream>>>(hs, w1, b1, w2, b2, out);
}